// Round 1
// baseline (167.151 us; speedup 1.0000x reference)
//
#include <hip/hip_runtime.h>
#include <hip/hip_bf16.h>
#include <math.h>

// Problem constants (fixed by setup_inputs)
#define S_   64
#define H_   32
#define D_   128
#define KVH_ 8
#define G_   4
#define BS_  16
#define MB_  128
#define NB_  4096
#define LMAX_ 2048

#define SCALE_ 0.08838834764831845f  // 1/sqrt(128)

// Partial kernel: one WG per (seq, kv_head, partition).
// 256 threads = 8 groups of 32 lanes. Group g handles tokens t0+g, t0+g+8, ...
// Each lane owns a 4-float slice of D (lane*4 .. lane*4+3).
__global__ __launch_bounds__(256)
void pa_partial(const float* __restrict__ q,
                const float* __restrict__ kc,
                const float* __restrict__ vc,
                const int* __restrict__ bt,
                const int* __restrict__ cl,
                float* __restrict__ ws,
                int PART, int maxP)
{
    const int s    = blockIdx.z;
    const int kvh  = blockIdx.y;
    const int part = blockIdx.x;

    const int len = cl[s];
    const int t0  = part * PART;
    if (t0 >= len) return;
    const int t1 = min(t0 + PART, len);

    const int tid  = threadIdx.x;
    const int gid  = tid >> 5;   // 0..7
    const int lane = tid & 31;   // 0..31

    // Q fragments: 4 heads, each lane holds float4 at d = lane*4
    float4 qv[G_];
#pragma unroll
    for (int g = 0; g < G_; ++g) {
        qv[g] = *(const float4*)(q + ((size_t)(s * H_ + kvh * G_ + g)) * D_ + lane * 4);
    }

    float  m[G_], l[G_];
    float4 acc[G_];
#pragma unroll
    for (int g = 0; g < G_; ++g) {
        m[g] = -INFINITY; l[g] = 0.f;
        acc[g] = make_float4(0.f, 0.f, 0.f, 0.f);
    }

    const int* btr = bt + s * MB_;
    const size_t kvh_off = (size_t)kvh * (BS_ * D_);

    for (int t = t0 + gid; t < t1; t += 8) {
        const int bid = btr[t >> 4];
        const size_t row = (size_t)bid * (KVH_ * BS_ * D_) + kvh_off + (size_t)(t & 15) * D_;
        const float4 k4 = *(const float4*)(kc + row + lane * 4);
        const float4 v4 = *(const float4*)(vc + row + lane * 4);

#pragma unroll
        for (int g = 0; g < G_; ++g) {
            float d0 = qv[g].x * k4.x + qv[g].y * k4.y + qv[g].z * k4.z + qv[g].w * k4.w;
#pragma unroll
            for (int off = 16; off; off >>= 1) d0 += __shfl_xor(d0, off, 32);
            const float sc = d0 * SCALE_;
            const float mn = fmaxf(m[g], sc);
            const float corr = __expf(m[g] - mn);  // exp(-inf - finite) = 0 on first token
            const float p    = __expf(sc - mn);
            l[g] = l[g] * corr + p;
            acc[g].x = acc[g].x * corr + p * v4.x;
            acc[g].y = acc[g].y * corr + p * v4.y;
            acc[g].z = acc[g].z * corr + p * v4.z;
            acc[g].w = acc[g].w * corr + p * v4.w;
            m[g] = mn;
        }
    }

    // Combine the 8 groups inside the WG via LDS.
    __shared__ float lm[8][G_];
    __shared__ float ll[8][G_];
    __shared__ float lacc[8][G_][D_];   // 16 KB

#pragma unroll
    for (int g = 0; g < G_; ++g) {
        if (lane == 0) { lm[gid][g] = m[g]; ll[gid][g] = l[g]; }
        *(float4*)&lacc[gid][g][lane * 4] = acc[g];
    }
    __syncthreads();

    // 512 (g,d) elements over 256 threads: 2 each.
    float* pbase = ws + (((size_t)(s * KVH_ + kvh) * maxP + part) * G_) * 130;
#pragma unroll
    for (int i = 0; i < 2; ++i) {
        const int idx = tid + 256 * i;
        const int g = idx >> 7;
        const int d = idx & 127;
        float M = lm[0][g];
#pragma unroll
        for (int r = 1; r < 8; ++r) M = fmaxf(M, lm[r][g]);
        float L = 0.f, val = 0.f;
#pragma unroll
        for (int r = 0; r < 8; ++r) {
            const float w = __expf(lm[r][g] - M);
            L   += w * ll[r][g];
            val += w * lacc[r][g][d];
        }
        float* pb = pbase + (size_t)g * 130;
        if (d == 0) { pb[0] = M; pb[1] = L; }
        pb[2 + d] = val;
    }
}

// Combine kernel: one WG (128 threads) per (seq, head); reduce over partitions.
__global__ __launch_bounds__(128)
void pa_combine(const float* __restrict__ ws,
                const int* __restrict__ cl,
                float* __restrict__ out,
                int PART, int maxP)
{
    const int h = blockIdx.x;   // 0..31
    const int s = blockIdx.y;   // 0..63
    const int kvh = h >> 2;
    const int g   = h & 3;
    const int d   = threadIdx.x;

    const int len = cl[s];
    const int np  = (len + PART - 1) / PART;

    const float* base = ws + ((size_t)(s * KVH_ + kvh) * maxP) * (G_ * 130) + (size_t)g * 130;

    float M = -INFINITY;
    for (int p = 0; p < np; ++p) M = fmaxf(M, base[(size_t)p * (G_ * 130)]);

    float L = 0.f, val = 0.f;
    for (int p = 0; p < np; ++p) {
        const float* pb = base + (size_t)p * (G_ * 130);
        const float w = __expf(pb[0] - M);
        L   += w * pb[1];
        val += w * pb[2 + d];
    }
    out[((size_t)s * H_ + h) * D_ + d] = val / L;
}

extern "C" void kernel_launch(void* const* d_in, const int* in_sizes, int n_in,
                              void* d_out, int out_size, void* d_ws, size_t ws_size,
                              hipStream_t stream)
{
    const float* q  = (const float*)d_in[0];
    const float* kc = (const float*)d_in[1];
    const float* vc = (const float*)d_in[2];
    const int*   bt = (const int*)d_in[3];
    const int*   cl = (const int*)d_in[4];
    float* out = (float*)d_out;
    float* ws  = (float*)d_ws;

    // Pick partition size so partials fit in workspace.
    int PART = 256;
    int maxP = LMAX_ / PART;
    while (PART < LMAX_) {
        size_t need = (size_t)S_ * KVH_ * maxP * G_ * 130 * sizeof(float);
        if (need <= ws_size) break;
        PART *= 2; maxP = LMAX_ / PART;
    }

    dim3 grid1(maxP, KVH_, S_);
    pa_partial<<<grid1, 256, 0, stream>>>(q, kc, vc, bt, cl, ws, PART, maxP);

    dim3 grid2(H_, S_);
    pa_combine<<<grid2, 128, 0, stream>>>(ws, cl, out, PART, maxP);
}

// Round 2
// 142.836 us; speedup vs baseline: 1.1702x; 1.1702x over previous
//
#include <hip/hip_runtime.h>
#include <hip/hip_bf16.h>
#include <math.h>

// Problem constants (fixed by setup_inputs)
#define S_   64
#define H_   32
#define D_   128
#define KVH_ 8
#define G_   4
#define BS_  16
#define MB_  128
#define LMAX_ 2048
#define TB_  4

#define SCALE_ 0.08838834764831845f  // 1/sqrt(128)

// Partial kernel: one WG per (seq, kv_head, partition of PART tokens).
// 256 threads = 8 groups of 32 lanes. Each group owns PART/128 consecutive
// 16-token pages (so one block-table entry per page, contiguous K/V rows).
// Lane owns a 4-float slice of D. Tokens processed in batches of TB_=4 for
// MLP (8 loads in flight) and ILP (16 independent shuffle-reduce chains).
__global__ __launch_bounds__(256, 4)
void pa_partial(const float* __restrict__ q,
                const float* __restrict__ kc,
                const float* __restrict__ vc,
                const int* __restrict__ bt,
                const int* __restrict__ cl,
                float* __restrict__ ws,
                int PART, int maxP)
{
    const int s    = blockIdx.z;
    const int kvh  = blockIdx.y;
    const int part = blockIdx.x;

    const int len = cl[s];
    const int t0  = part * PART;
    if (t0 >= len) return;
    const int t1 = min(t0 + PART, len);

    const int tid  = threadIdx.x;
    const int gid  = tid >> 5;   // 0..7
    const int lane = tid & 31;   // 0..31

    const int nblk = PART >> 7;  // 16-token pages per group

    // Q fragments: 4 heads, each lane holds float4 at d = lane*4
    float4 qv[G_];
#pragma unroll
    for (int g = 0; g < G_; ++g)
        qv[g] = *(const float4*)(q + ((size_t)(s * H_ + kvh * G_ + g)) * D_ + lane * 4);

    float  m[G_], l[G_];
    float4 acc[G_];
#pragma unroll
    for (int g = 0; g < G_; ++g) {
        m[g] = -INFINITY; l[g] = 0.f;
        acc[g] = make_float4(0.f, 0.f, 0.f, 0.f);
    }

    const int* btr = bt + s * MB_;
    const size_t kvh_off = (size_t)kvh * (BS_ * D_);

    for (int b = 0; b < nblk; ++b) {
        const int tblk = t0 + (gid * nblk + b) * BS_;   // start of this 16-token page
        if (tblk >= t1) break;
        const int bid = btr[tblk >> 4];
        const float* kb = kc + (size_t)bid * (KVH_ * BS_ * D_) + kvh_off + lane * 4;
        const float* vb = vc + (size_t)bid * (KVH_ * BS_ * D_) + kvh_off + lane * 4;
        const int tend = min(tblk + BS_, t1);

#pragma unroll
        for (int tbi = 0; tbi < BS_ / TB_; ++tbi) {
            const int tb = tblk + tbi * TB_;
            if (tb >= tend) break;

            float4 k4[TB_], v4[TB_];
#pragma unroll
            for (int i = 0; i < TB_; ++i) {
                k4[i] = *(const float4*)(kb + (size_t)(tbi * TB_ + i) * D_);
                v4[i] = *(const float4*)(vb + (size_t)(tbi * TB_ + i) * D_);
            }

            // Partial dots: 16 independent values
            float sc[TB_][G_];
#pragma unroll
            for (int i = 0; i < TB_; ++i)
#pragma unroll
                for (int g = 0; g < G_; ++g)
                    sc[i][g] = qv[g].x * k4[i].x + qv[g].y * k4[i].y +
                               qv[g].z * k4[i].z + qv[g].w * k4[i].w;

            // Butterfly reduce across 32 lanes; 16 chains pipeline.
#pragma unroll
            for (int off = 16; off; off >>= 1)
#pragma unroll
                for (int i = 0; i < TB_; ++i)
#pragma unroll
                    for (int g = 0; g < G_; ++g)
                        sc[i][g] += __shfl_xor(sc[i][g], off, 32);

            // Scale + mask invalid tokens (loads above are always in-bounds:
            // any row of a valid page exists).
#pragma unroll
            for (int i = 0; i < TB_; ++i) {
                const bool valid = (tb + i) < t1;
#pragma unroll
                for (int g = 0; g < G_; ++g)
                    sc[i][g] = valid ? sc[i][g] * SCALE_ : -INFINITY;
            }

            // Batched online-softmax update (one corr per head per 4 tokens).
            // tb < tend guarantees sc[0][g] finite -> mn finite.
#pragma unroll
            for (int g = 0; g < G_; ++g) {
                const float smax = fmaxf(fmaxf(sc[0][g], sc[1][g]),
                                         fmaxf(sc[2][g], sc[3][g]));
                const float mn   = fmaxf(m[g], smax);
                const float corr = __expf(m[g] - mn);   // m=-inf first time -> 0
                const float p0 = __expf(sc[0][g] - mn);
                const float p1 = __expf(sc[1][g] - mn);
                const float p2 = __expf(sc[2][g] - mn);
                const float p3 = __expf(sc[3][g] - mn);
                l[g] = l[g] * corr + ((p0 + p1) + (p2 + p3));
                acc[g].x = acc[g].x * corr + p0 * v4[0].x + p1 * v4[1].x + p2 * v4[2].x + p3 * v4[3].x;
                acc[g].y = acc[g].y * corr + p0 * v4[0].y + p1 * v4[1].y + p2 * v4[2].y + p3 * v4[3].y;
                acc[g].z = acc[g].z * corr + p0 * v4[0].z + p1 * v4[1].z + p2 * v4[2].z + p3 * v4[3].z;
                acc[g].w = acc[g].w * corr + p0 * v4[0].w + p1 * v4[1].w + p2 * v4[2].w + p3 * v4[3].w;
                m[g] = mn;
            }
        }
    }

    // Combine the 8 groups inside the WG via LDS.
    __shared__ float lm[8][G_];
    __shared__ float ll[8][G_];
    __shared__ float lacc[8][G_][D_];   // 16 KB

#pragma unroll
    for (int g = 0; g < G_; ++g) {
        if (lane == 0) { lm[gid][g] = m[g]; ll[gid][g] = l[g]; }
        *(float4*)&lacc[gid][g][lane * 4] = acc[g];
    }
    __syncthreads();

    // 512 (g,d) elements over 256 threads: 2 each.
    float* pbase = ws + (((size_t)(s * KVH_ + kvh) * maxP + part) * G_) * 130;
#pragma unroll
    for (int i = 0; i < 2; ++i) {
        const int idx = tid + 256 * i;
        const int g = idx >> 7;
        const int d = idx & 127;
        float M = lm[0][g];
#pragma unroll
        for (int r = 1; r < 8; ++r) M = fmaxf(M, lm[r][g]);
        float L = 0.f, val = 0.f;
#pragma unroll
        for (int r = 0; r < 8; ++r) {
            const float w = __expf(lm[r][g] - M);
            L   += w * ll[r][g];
            val += w * lacc[r][g][d];
        }
        float* pb = pbase + (size_t)g * 130;
        if (d == 0) { pb[0] = M; pb[1] = L; }
        pb[2 + d] = val;
    }
}

// Combine kernel: one WG (128 threads) per (seq, head); reduce over partitions.
__global__ __launch_bounds__(128)
void pa_combine(const float* __restrict__ ws,
                const int* __restrict__ cl,
                float* __restrict__ out,
                int PART, int maxP)
{
    const int h = blockIdx.x;   // 0..31
    const int s = blockIdx.y;   // 0..63
    const int kvh = h >> 2;
    const int g   = h & 3;
    const int d   = threadIdx.x;

    const int len = cl[s];
    const int np  = (len + PART - 1) / PART;

    const float* base = ws + ((size_t)(s * KVH_ + kvh) * maxP) * (G_ * 130) + (size_t)g * 130;

    float M = -INFINITY;
    for (int p = 0; p < np; ++p) M = fmaxf(M, base[(size_t)p * (G_ * 130)]);

    float L = 0.f, val = 0.f;
    for (int p = 0; p < np; ++p) {
        const float* pb = base + (size_t)p * (G_ * 130);
        const float w = __expf(pb[0] - M);
        L   += w * pb[1];
        val += w * pb[2 + d];
    }
    out[((size_t)s * H_ + h) * D_ + d] = val / L;
}

extern "C" void kernel_launch(void* const* d_in, const int* in_sizes, int n_in,
                              void* d_out, int out_size, void* d_ws, size_t ws_size,
                              hipStream_t stream)
{
    const float* q  = (const float*)d_in[0];
    const float* kc = (const float*)d_in[1];
    const float* vc = (const float*)d_in[2];
    const int*   bt = (const int*)d_in[3];
    const int*   cl = (const int*)d_in[4];
    float* out = (float*)d_out;
    float* ws  = (float*)d_ws;

    // Pick partition size so partials fit in workspace (prefer small PART
    // for load balance; must be a multiple of 128).
    int PART = 128;
    int maxP = LMAX_ / PART;
    while (PART < LMAX_) {
        size_t need = (size_t)S_ * KVH_ * maxP * G_ * 130 * sizeof(float);
        if (need <= ws_size) break;
        PART *= 2; maxP = LMAX_ / PART;
    }

    dim3 grid1(maxP, KVH_, S_);
    pa_partial<<<grid1, 256, 0, stream>>>(q, kc, vc, bt, cl, ws, PART, maxP);

    dim3 grid2(H_, S_);
    pa_combine<<<grid2, 128, 0, stream>>>(ws, cl, out, PART, maxP);
}

// Round 3
// 140.820 us; speedup vs baseline: 1.1870x; 1.0143x over previous
//
#include <hip/hip_runtime.h>
#include <hip/hip_bf16.h>
#include <math.h>

// Problem constants (fixed by setup_inputs)
#define S_   64
#define H_   32
#define D_   128
#define KVH_ 8
#define G_   4
#define BS_  16
#define MB_  128
#define LMAX_ 2048

#define SCALE_ 0.08838834764831845f  // 1/sqrt(128)

// Partial kernel: one WG per (seq, kv_head, partition of PART=256 tokens).
// 256 threads = 8 groups of 32 lanes. Each group owns 2 consecutive 16-token
// pages (32 tokens) processed in 8 batches of 4, with explicit K/V register
// double-buffering: batch i+1's loads are issued before batch i's compute.
// Lane owns a 4-float slice of D (one float4 per K/V row).
__global__ __launch_bounds__(256)
void pa_partial(const float* __restrict__ q,
                const float* __restrict__ kc,
                const float* __restrict__ vc,
                const int* __restrict__ bt,
                const int* __restrict__ cl,
                float* __restrict__ ws,
                int PART, int maxP)
{
    const int s    = blockIdx.z;
    const int kvh  = blockIdx.y;
    const int part = blockIdx.x;

    const int len = cl[s];
    const int t0  = part * PART;
    if (t0 >= len) return;
    const int t1 = min(t0 + PART, len);

    const int tid  = threadIdx.x;
    const int gid  = tid >> 5;   // 0..7
    const int lane = tid & 31;   // 0..31

    // Q fragments: 4 heads, each lane holds float4 at d = lane*4
    float4 qv[G_];
#pragma unroll
    for (int g = 0; g < G_; ++g)
        qv[g] = *(const float4*)(q + ((size_t)(s * H_ + kvh * G_ + g)) * D_ + lane * 4);

    float  m[G_], l[G_];
    float4 acc[G_];
#pragma unroll
    for (int g = 0; g < G_; ++g) {
        m[g] = -INFINITY; l[g] = 0.f;
        acc[g] = make_float4(0.f, 0.f, 0.f, 0.f);
    }

    const int* btr = bt + s * MB_;
    const size_t kvh_off = (size_t)kvh * (BS_ * D_);

    const int t_base  = t0 + gid * 32;     // group's first token
    const int navail  = t1 - t_base;       // tokens this group must process

    if (navail > 0) {
        // Two pages cover the group's 32 tokens. page0+1 <= 127 always.
        const int page0 = t_base >> 4;
        const int bid0  = btr[page0];
        const int bid1  = btr[page0 + 1];
        const float* kp0 = kc + (size_t)bid0 * (KVH_ * BS_ * D_) + kvh_off + lane * 4;
        const float* vp0 = vc + (size_t)bid0 * (KVH_ * BS_ * D_) + kvh_off + lane * 4;
        const float* kp1 = kc + (size_t)bid1 * (KVH_ * BS_ * D_) + kvh_off + lane * 4;
        const float* vp1 = vc + (size_t)bid1 * (KVH_ * BS_ * D_) + kvh_off + lane * 4;

        const int nb = min(8, (navail + 3) >> 2);   // 4-token batches

        float4 kb[2][4], vb[2][4];
        // Prologue: load batch 0 (page 0, rows 0..3)
#pragma unroll
        for (int r = 0; r < 4; ++r) {
            kb[0][r] = *(const float4*)(kp0 + (size_t)r * D_);
            vb[0][r] = *(const float4*)(vp0 + (size_t)r * D_);
        }

#pragma unroll
        for (int i = 0; i < 8; ++i) {
            if (i >= nb) break;
            const int cur = i & 1, nxt = cur ^ 1;

            // Prefetch batch i+1 (issued before consuming batch i).
            if (i + 1 < nb) {
                const float* kpp = ((i + 1) < 4 ? kp0 : kp1) + (size_t)(((i + 1) & 3) * 4) * D_;
                const float* vpp = ((i + 1) < 4 ? vp0 : vp1) + (size_t)(((i + 1) & 3) * 4) * D_;
#pragma unroll
                for (int r = 0; r < 4; ++r) {
                    kb[nxt][r] = *(const float4*)(kpp + (size_t)r * D_);
                    vb[nxt][r] = *(const float4*)(vpp + (size_t)r * D_);
                }
            }

            // Partial dots: 16 independent values
            float sc[4][G_];
#pragma unroll
            for (int i2 = 0; i2 < 4; ++i2)
#pragma unroll
                for (int g = 0; g < G_; ++g)
                    sc[i2][g] = qv[g].x * kb[cur][i2].x + qv[g].y * kb[cur][i2].y +
                                qv[g].z * kb[cur][i2].z + qv[g].w * kb[cur][i2].w;

            // Butterfly reduce across 32 lanes; 16 chains pipeline.
#pragma unroll
            for (int off = 16; off; off >>= 1)
#pragma unroll
                for (int i2 = 0; i2 < 4; ++i2)
#pragma unroll
                    for (int g = 0; g < G_; ++g)
                        sc[i2][g] += __shfl_xor(sc[i2][g], off, 32);

            // Scale + mask tokens beyond navail.
#pragma unroll
            for (int i2 = 0; i2 < 4; ++i2) {
                const bool valid = (i * 4 + i2) < navail;
#pragma unroll
                for (int g = 0; g < G_; ++g)
                    sc[i2][g] = valid ? sc[i2][g] * SCALE_ : -INFINITY;
            }

            // Batched online-softmax update (one corr per head per 4 tokens).
#pragma unroll
            for (int g = 0; g < G_; ++g) {
                const float smax = fmaxf(fmaxf(sc[0][g], sc[1][g]),
                                         fmaxf(sc[2][g], sc[3][g]));
                const float mn   = fmaxf(m[g], smax);
                const float corr = __expf(m[g] - mn);   // m=-inf first time -> 0
                const float p0 = __expf(sc[0][g] - mn);
                const float p1 = __expf(sc[1][g] - mn);
                const float p2 = __expf(sc[2][g] - mn);
                const float p3 = __expf(sc[3][g] - mn);
                l[g] = l[g] * corr + ((p0 + p1) + (p2 + p3));
                acc[g].x = acc[g].x * corr + p0 * vb[cur][0].x + p1 * vb[cur][1].x + p2 * vb[cur][2].x + p3 * vb[cur][3].x;
                acc[g].y = acc[g].y * corr + p0 * vb[cur][0].y + p1 * vb[cur][1].y + p2 * vb[cur][2].y + p3 * vb[cur][3].y;
                acc[g].z = acc[g].z * corr + p0 * vb[cur][0].z + p1 * vb[cur][1].z + p2 * vb[cur][2].z + p3 * vb[cur][3].z;
                acc[g].w = acc[g].w * corr + p0 * vb[cur][0].w + p1 * vb[cur][1].w + p2 * vb[cur][2].w + p3 * vb[cur][3].w;
                m[g] = mn;
            }
        }
    }

    // Combine the 8 groups inside the WG via LDS.
    __shared__ float lm[8][G_];
    __shared__ float ll[8][G_];
    __shared__ float lacc[8][G_][D_];   // 16 KB

#pragma unroll
    for (int g = 0; g < G_; ++g) {
        if (lane == 0) { lm[gid][g] = m[g]; ll[gid][g] = l[g]; }
        *(float4*)&lacc[gid][g][lane * 4] = acc[g];
    }
    __syncthreads();

    // 512 (g,d) elements over 256 threads: 2 each.
    float* pbase = ws + (((size_t)(s * KVH_ + kvh) * maxP + part) * G_) * 130;
#pragma unroll
    for (int i = 0; i < 2; ++i) {
        const int idx = tid + 256 * i;
        const int g = idx >> 7;
        const int d = idx & 127;
        float M = lm[0][g];
#pragma unroll
        for (int r = 1; r < 8; ++r) M = fmaxf(M, lm[r][g]);
        float L = 0.f, val = 0.f;
#pragma unroll
        for (int r = 0; r < 8; ++r) {
            const float w = __expf(lm[r][g] - M);   // lm=-inf (empty group) -> 0
            L   += w * ll[r][g];
            val += w * lacc[r][g][d];
        }
        float* pb = pbase + (size_t)g * 130;
        if (d == 0) { pb[0] = M; pb[1] = L; }
        pb[2 + d] = val;
    }
}

// Combine kernel: one WG (128 threads) per (seq, head); reduce over partitions.
__global__ __launch_bounds__(128)
void pa_combine(const float* __restrict__ ws,
                const int* __restrict__ cl,
                float* __restrict__ out,
                int PART, int maxP)
{
    const int h = blockIdx.x;   // 0..31
    const int s = blockIdx.y;   // 0..63
    const int kvh = h >> 2;
    const int g   = h & 3;
    const int d   = threadIdx.x;

    const int len = cl[s];
    const int np  = (len + PART - 1) / PART;

    const float* base = ws + ((size_t)(s * KVH_ + kvh) * maxP) * (G_ * 130) + (size_t)g * 130;

    float M = -INFINITY;
    for (int p = 0; p < np; ++p) M = fmaxf(M, base[(size_t)p * (G_ * 130)]);

    float L = 0.f, val = 0.f;
    for (int p = 0; p < np; ++p) {
        const float* pb = base + (size_t)p * (G_ * 130);
        const float w = __expf(pb[0] - M);
        L   += w * pb[1];
        val += w * pb[2 + d];
    }
    out[((size_t)s * H_ + h) * D_ + d] = val / L;
}

extern "C" void kernel_launch(void* const* d_in, const int* in_sizes, int n_in,
                              void* d_out, int out_size, void* d_ws, size_t ws_size,
                              hipStream_t stream)
{
    const float* q  = (const float*)d_in[0];
    const float* kc = (const float*)d_in[1];
    const float* vc = (const float*)d_in[2];
    const int*   bt = (const int*)d_in[3];
    const int*   cl = (const int*)d_in[4];
    float* out = (float*)d_out;
    float* ws  = (float*)d_ws;

    // PART=256 tokens (2 pages per 32-lane group); grow if ws too small.
    int PART = 256;
    int maxP = LMAX_ / PART;
    while (PART < LMAX_) {
        size_t need = (size_t)S_ * KVH_ * maxP * G_ * 130 * sizeof(float);
        if (need <= ws_size) break;
        PART *= 2; maxP = LMAX_ / PART;
    }

    dim3 grid1(maxP, KVH_, S_);
    pa_partial<<<grid1, 256, 0, stream>>>(q, kc, vc, bt, cl, ws, PART, maxP);

    dim3 grid2(H_, S_);
    pa_combine<<<grid2, 128, 0, stream>>>(ws, cl, out, PART, maxP);
}